// Round 10
// baseline (297.689 us; speedup 1.0000x reference)
//
#include <hip/hip_runtime.h>
#include <math.h>

#define HEADS 16
#define DIM_HEAD 64
#define DIM 1024
#define INNER 1024
#define SEQ 2048
#define BATCH 4
#define ROWS (BATCH * SEQ)   // 8192

typedef _Float16 v8h __attribute__((ext_vector_type(8)));
typedef _Float16 v4h __attribute__((ext_vector_type(4)));
typedef _Float16 v2h __attribute__((ext_vector_type(2)));
typedef __fp16   v2fp __attribute__((ext_vector_type(2)));
typedef float    v4f __attribute__((ext_vector_type(4)));

static __device__ __forceinline__ v2h pk_exp2_h2(float a, float b) {
    v2fp r = __builtin_amdgcn_cvt_pkrtz(__builtin_amdgcn_exp2f(a),
                                        __builtin_amdgcn_exp2f(b));
    return __builtin_bit_cast(v2h, r);
}

// async global->LDS, 16B per lane; LDS dst is wave-uniform base + lane*16
#define GLOAD_LDS16(gptr, lptr)                                                   \
    __builtin_amdgcn_global_load_lds(                                             \
        (const __attribute__((address_space(1))) void*)(gptr),                    \
        (__attribute__((address_space(3))) void*)(lptr), 16, 0, 0)

// ---------------- merged preprocessing: LN + 2x weight-convert + rope table ----------------
__global__ __launch_bounds__(256) void prep_kernel(const float* __restrict__ x,
                                                   const float* __restrict__ g,
                                                   const float* __restrict__ bvec,
                                                   _Float16* __restrict__ xn,
                                                   const float* __restrict__ w_qkv,
                                                   _Float16* __restrict__ W1t,
                                                   const float* __restrict__ w_out,
                                                   _Float16* __restrict__ W2t,
                                                   float2* __restrict__ tab) {
    __shared__ __align__(16) char pmem[64 * 72 * 2];   // wcvt tile; ln reuses first 2KB
    const int bid = blockIdx.x;
    const int tid = threadIdx.x;

    if (bid < ROWS) {
        // ---- LayerNorm: one block per row, fp16 out ----
        float2* red = (float2*)pmem;
        const float* xr = x + (size_t)bid * DIM;
        float4 v = *(const float4*)(xr + tid * 4);
        float s  = v.x + v.y + v.z + v.w;
        float ss = v.x * v.x + v.y * v.y + v.z * v.z + v.w * v.w;
        red[tid] = make_float2(s, ss);
        __syncthreads();
        for (int off = 128; off > 0; off >>= 1) {
            if (tid < off) {
                red[tid].x += red[tid + off].x;
                red[tid].y += red[tid + off].y;
            }
            __syncthreads();
        }
        const float mu  = red[0].x * (1.0f / DIM);
        const float var = red[0].y * (1.0f / DIM) - mu * mu;
        const float rinv = rsqrtf(var + 1e-5f);
        const int c = tid * 4;
        float4 gg = *(const float4*)(g + c);
        float4 bb = *(const float4*)(bvec + c);
        v4h o;
        o[0] = (_Float16)((v.x - mu) * rinv * gg.x + bb.x);
        o[1] = (_Float16)((v.y - mu) * rinv * gg.y + bb.y);
        o[2] = (_Float16)((v.z - mu) * rinv * gg.z + bb.z);
        o[3] = (_Float16)((v.w - mu) * rinv * gg.w + bb.w);
        *(v4h*)(xn + (size_t)bid * DIM + c) = o;
    } else if (bid < ROWS + 768 + 256) {
        // ---- weight convert + transpose: W[K][N] f32 -> Wt[N][K] fp16 ----
        const float* W; _Float16* Wt; int K, N, j0, i0;
        if (bid < ROWS + 768) {
            const int t = bid - ROWS;            // grid was (48, 16)
            W = w_qkv; Wt = W1t; K = DIM; N = 3 * INNER;
            j0 = (t % 48) * 64; i0 = (t / 48) * 64;
        } else {
            const int t = bid - ROWS - 768;      // grid was (16, 16)
            W = w_out; Wt = W2t; K = INNER; N = DIM;
            j0 = (t % 16) * 64; i0 = (t / 16) * 64;
        }
        _Float16 (*T)[72] = (_Float16(*)[72])pmem;
        const int row = tid >> 2;
        const int cs  = (tid & 3) * 16;
#pragma unroll
        for (int e = 0; e < 16; e += 4) {
            float4 v = *(const float4*)(W + (size_t)(i0 + row) * N + j0 + cs + e);
            T[cs + e + 0][row] = (_Float16)v.x;
            T[cs + e + 1][row] = (_Float16)v.y;
            T[cs + e + 2][row] = (_Float16)v.z;
            T[cs + e + 3][row] = (_Float16)v.w;
        }
        __syncthreads();
        v8h o0 = *(const v8h*)&T[row][cs];
        v8h o1 = *(const v8h*)&T[row][cs + 8];
        *(v8h*)(Wt + (size_t)(j0 + row) * K + i0 + cs) = o0;
        *(v8h*)(Wt + (size_t)(j0 + row) * K + i0 + cs + 8) = o1;
    } else {
        // ---- RoPE cos/sin table: [SEQ][64] of (cos, sin) ----
        const int idx = (bid - (ROWS + 1024)) * 256 + tid;
        const int n = idx >> 6, d = idx & 63;
        const float ang = (float)n * exp2f((float)(d >> 1) * (-13.287712379549449f / 32.0f));
        float s, c;
        sincosf(ang, &s, &c);
        tab[idx] = make_float2(c, s);
    }
}

// ---------------- fused QKV GEMM + RoPE + repack (ROUND-7 VERSION, reverted) ----------------
// BK=64, XOR-swizzled LDS, single-buffer vmcnt-drain loop. The round-9 counted-vmcnt
// dbuf experiment was null (-3.7us) -- within-session replication of the catalog's
// regime gate (counted vmcnt without the full 8-phase interleave does nothing at 128²).
#define QSCALE 0.18033688011112042f  /* log2(e)/8 */
__global__ __launch_bounds__(256) void gemm_qkv_rope(const _Float16* __restrict__ A,
                                                     const _Float16* __restrict__ Bt,
                                                     const float2* __restrict__ tab,
                                                     _Float16* __restrict__ Qh,
                                                     _Float16* __restrict__ Kh,
                                                     _Float16* __restrict__ Vtg) {
    const int N = 3 * INNER, K = DIM;
    // union: main loop uses As/Bs (32 KB); Q/K epilogue reuses as Ts (34 KB)
    __shared__ __align__(16) char smem[34816];
    _Float16* As = (_Float16*)smem;             // [128][64] halves, swizzled slots
    _Float16* Bs = (_Float16*)(smem + 16384);   // [128][64]
    _Float16* Ts = (_Float16*)smem;             // [4][64][68] epilogue transpose

    const int tid = threadIdx.x;
    const int w = tid >> 6, lane = tid & 63;
    const int l15 = lane & 15, grp = lane >> 4;
    const int wm = w >> 1, wn = w & 1;
    const int m0 = blockIdx.y * 128, n0 = blockIdx.x * 128;

    const int srow7 = (tid >> 3) & 7;           // row&7 for the staged row
    const int sslot = (tid & 7) ^ srow7;        // swizzled source slot

    v4f acc[4][4];
#pragma unroll
    for (int i = 0; i < 4; ++i)
#pragma unroll
        for (int j = 0; j < 4; ++j) acc[i][j] = (v4f){0.f, 0.f, 0.f, 0.f};

    for (int k0 = 0; k0 < K; k0 += 64) {
#pragma unroll
        for (int q = 0; q < 4; ++q) {
            const int row = q * 32 + (tid >> 3);
            GLOAD_LDS16(A  + (size_t)(m0 + row) * K + k0 + sslot * 8, As + q * 2048 + tid * 8);
            GLOAD_LDS16(Bt + (size_t)(n0 + row) * K + k0 + sslot * 8, Bs + q * 2048 + tid * 8);
        }
        __syncthreads();

#pragma unroll
        for (int ks = 0; ks < 2; ++ks) {
            const int sl = ((ks * 4 + grp) ^ (l15 & 7)) * 8;  // swizzled col (halves)
            v8h a[4], bf[4];
#pragma unroll
            for (int i = 0; i < 4; ++i) {
                a[i]  = *(const v8h*)(As + (size_t)(wm * 64 + i * 16 + l15) * 64 + sl);
                bf[i] = *(const v8h*)(Bs + (size_t)(wn * 64 + i * 16 + l15) * 64 + sl);
            }
#pragma unroll
            for (int mb = 0; mb < 4; ++mb)
#pragma unroll
                for (int nb = 0; nb < 4; ++nb)
                    acc[mb][nb] = __builtin_amdgcn_mfma_f32_16x16x32_f16(a[mb], bf[nb], acc[mb][nb], 0, 0, 0);
        }
        __syncthreads();
    }

    const int mrow = m0 + wm * 64;       // token-row base (64-aligned)
    const int ncol = n0 + wn * 64;       // qkv-col base (one head section)
    const int sec   = ncol >> 10;        // 0=q, 1=k, 2=v (block-uniform)
    const int h     = (ncol >> 6) & 15;
    const int b     = mrow >> 11;
    const int nbase = mrow & (SEQ - 1);
    const int bh    = b * 16 + h;

    if (sec == 2) {
        // V: transposed store Vtg[bh][d][n], 4 consecutive n per 8B store
#pragma unroll
        for (int nb = 0; nb < 4; ++nb) {
            const int d = nb * 16 + l15;
            _Float16* vdst = Vtg + ((size_t)bh * 64 + d) * SEQ;
#pragma unroll
            for (int mb = 0; mb < 4; ++mb) {
                const int n = nbase + mb * 16 + grp * 4;
                v4h o;
                o[0] = (_Float16)acc[mb][nb][0];
                o[1] = (_Float16)acc[mb][nb][1];
                o[2] = (_Float16)acc[mb][nb][2];
                o[3] = (_Float16)acc[mb][nb][3];
                *(v4h*)(vdst + n) = o;
            }
        }
    } else {
        _Float16* dst  = (sec == 0) ? Qh : Kh;
        const float qs = (sec == 0) ? QSCALE : 1.0f;
        _Float16* Tw = Ts + (size_t)w * (64 * 68);
        // rope in-register, land in per-wave LDS tile [n_local][d]
#pragma unroll
        for (int mb = 0; mb < 4; ++mb) {
#pragma unroll
            for (int r = 0; r < 4; ++r) {
                const int nl = mb * 16 + grp * 4 + r;
                const float2* tn = tab + (((size_t)(nbase + nl)) << 6);
#pragma unroll
                for (int nb = 0; nb < 4; ++nb) {
                    const int d = nb * 16 + l15;
                    const float2 cs = tn[d];
                    const float partner = acc[mb][nb ^ 2][r];
                    const float sg = (nb < 2) ? -cs.y : cs.y;
                    Tw[nl * 68 + d] = (_Float16)((acc[mb][nb][r] * cs.x + partner * sg) * qs);
                }
            }
        }
        __syncthreads();
        // coalesced 128B-row stores: 4 passes x (16 rows, 32B per lane)
#pragma unroll
        for (int p = 0; p < 4; ++p) {
            const int rr = p * 16 + (lane >> 2);
            const int cc = (lane & 3) * 16;
            v8h x0 = *(const v8h*)&Tw[rr * 68 + cc];
            v8h x1 = *(const v8h*)&Tw[rr * 68 + cc + 8];
            _Float16* gd = dst + ((size_t)bh * SEQ + nbase + rr) * 64 + cc;
            *(v8h*)gd = x0;
            *(v8h*)(gd + 8) = x1;
        }
    }
}

// ---------------- output-projection GEMM: fp32 out + bias ----------------
// RE-TILED this round: 128(M) x 64(N) tiles -> grid (16,64) = 1024 blocks = 4/CU
// (was 512 = 2/CU: half the TLP of the qkv gemm with the same latency-exposed
// loop). BK=64 with the round-7-proven XOR swizzle (conflict-free b128 reads).
// 4 waves as 2x2 over (128 x 64); wave tile 64x32, acc[4][2]. LDS 24KB.
__global__ __launch_bounds__(256) void gemm_nt_f(const _Float16* __restrict__ A,
                                                 const _Float16* __restrict__ Bt,
                                                 const float* __restrict__ bias,
                                                 float* __restrict__ C,
                                                 int M, int N, int K) {
    __shared__ __align__(16) _Float16 As[128 * 64];   // 16 KB
    __shared__ __align__(16) _Float16 Bs[64 * 64];    // 8 KB
    const int tid = threadIdx.x;
    const int w = tid >> 6, lane = tid & 63;
    const int l15 = lane & 15, grp = lane >> 4;
    const int wm = w >> 1, wn = w & 1;
    const int m0 = blockIdx.y * 128, n0 = blockIdx.x * 64;

    v4f acc[4][2];
#pragma unroll
    for (int i = 0; i < 4; ++i)
#pragma unroll
        for (int j = 0; j < 2; ++j) acc[i][j] = (v4f){0.f, 0.f, 0.f, 0.f};

    for (int k0 = 0; k0 < K; k0 += 64) {
        // A: 128 rows x 8 granules = 1024; 4 instr/thread. B: 64 x 8 = 512; 2 instr.
#pragma unroll
        for (int r = 0; r < 4; ++r) {
            const int glin = r * 256 + tid;
            const int row = glin >> 3, gcol = glin & 7;
            GLOAD_LDS16(A + (size_t)(m0 + row) * K + k0 + ((gcol ^ (row & 7)) * 8),
                        As + glin * 8);
        }
#pragma unroll
        for (int r = 0; r < 2; ++r) {
            const int glin = r * 256 + tid;
            const int row = glin >> 3, gcol = glin & 7;
            GLOAD_LDS16(Bt + (size_t)(n0 + row) * K + k0 + ((gcol ^ (row & 7)) * 8),
                        Bs + glin * 8);
        }
        __syncthreads();

#pragma unroll
        for (int ks = 0; ks < 2; ++ks) {
            const int sl = ((ks * 4 + grp) ^ (l15 & 7)) * 8;  // swizzled col (halves)
            v8h a[4], bf[2];
#pragma unroll
            for (int i = 0; i < 4; ++i)
                a[i] = *(const v8h*)(As + (size_t)(wm * 64 + i * 16 + l15) * 64 + sl);
#pragma unroll
            for (int j = 0; j < 2; ++j)
                bf[j] = *(const v8h*)(Bs + (size_t)(wn * 32 + j * 16 + l15) * 64 + sl);
#pragma unroll
            for (int mb = 0; mb < 4; ++mb)
#pragma unroll
                for (int nb = 0; nb < 2; ++nb)
                    acc[mb][nb] = __builtin_amdgcn_mfma_f32_16x16x32_f16(a[mb], bf[nb], acc[mb][nb], 0, 0, 0);
        }
        __syncthreads();
    }

    const int mrow = m0 + wm * 64;
    const int ncol = n0 + wn * 32;
#pragma unroll
    for (int nb = 0; nb < 2; ++nb) {
        const float bs = bias[ncol + nb * 16 + l15];
#pragma unroll
        for (int mb = 0; mb < 4; ++mb)
#pragma unroll
            for (int r = 0; r < 4; ++r)
                C[(size_t)(mrow + mb * 16 + grp * 4 + r) * N + ncol + nb * 16 + l15] =
                    acc[mb][nb][r] + bs;
    }
}

// ---------------- MFMA flash attention: 64 queries/wave, 256/block (UNCHANGED control) ----------------
#define SM_OFF2 7.2134752044448170f  /* 5 * log2(e) */
__global__ __launch_bounds__(256, 2) void fa_kernel(const _Float16* __restrict__ Qh,
                                                    const _Float16* __restrict__ Kh,
                                                    const _Float16* __restrict__ Vtg,
                                                    _Float16* __restrict__ out) {
    const int i = blockIdx.x;                 // 512 blocks
    const int bh = (i & 7) + ((i >> 6) << 3); // head bh -> XCD bh%8
    const int qblk = (i >> 3) & 7;            // 8 q-blocks of 256
    const int b = bh >> 4, h = bh & 15;
    const int tid = threadIdx.x;
    const int w = tid >> 6;
    const int lane = tid & 63;
    const int l15 = lane & 15;
    const int grp = lane >> 4;

    __shared__ _Float16 Ks[2][64][68];
    __shared__ _Float16 Vts[2][64][68];

    // Q fragments: wave w owns queries [qblk*256 + w*64, +64)
    v8h Qf[4][2];
    const _Float16* Qbase = Qh + ((size_t)bh * SEQ + qblk * 256 + w * 64) * 64;
#pragma unroll
    for (int nb = 0; nb < 4; ++nb)
#pragma unroll
        for (int ks = 0; ks < 2; ++ks)
            Qf[nb][ks] = *(const v8h*)(Qbase + (size_t)(nb * 16 + l15) * 64 + ks * 32 + grp * 8);

    float l_[4] = {0.f, 0.f, 0.f, 0.f};
    v4f O[4][4];
#pragma unroll
    for (int db = 0; db < 4; ++db)
#pragma unroll
        for (int nb = 0; nb < 4; ++nb) O[db][nb] = (v4f){0.f, 0.f, 0.f, 0.f};

    const int srow = tid >> 2;
    const int sseg = tid & 3;
    const _Float16* kp = Kh + (size_t)bh * SEQ * 64 + (size_t)srow * 64 + sseg * 16;
    const _Float16* vp = Vtg + (size_t)bh * 64 * SEQ + (size_t)srow * SEQ + sseg * 16;

    const v2h one2 = {(_Float16)1.0f, (_Float16)1.0f};

    // prologue: tile 0 -> LDS buf0; issue tile 1 -> regs
    v8h kr0 = *(const v8h*)(kp);
    v8h kr1 = *(const v8h*)(kp + 8);
    v8h vr0 = *(const v8h*)(vp);
    v8h vr1 = *(const v8h*)(vp + 8);
    *(v8h*)&Ks[0][srow][sseg * 16]      = kr0;
    *(v8h*)&Ks[0][srow][sseg * 16 + 8]  = kr1;
    *(v8h*)&Vts[0][srow][sseg * 16]     = vr0;
    *(v8h*)&Vts[0][srow][sseg * 16 + 8] = vr1;
    __syncthreads();
    kr0 = *(const v8h*)(kp + 64 * 64);
    kr1 = *(const v8h*)(kp + 64 * 64 + 8);
    vr0 = *(const v8h*)(vp + 64);
    vr1 = *(const v8h*)(vp + 64 + 8);

    for (int t = 0; t < SEQ / 64; ++t) {
        const int cur = t & 1;

        __builtin_amdgcn_s_setprio(1);
#pragma unroll
        for (int m = 0; m < 4; ++m) {
            v8h a0 = *(const v8h*)&Ks[cur][m * 16 + l15][grp * 8];
            v8h a1 = *(const v8h*)&Ks[cur][m * 16 + l15][32 + grp * 8];
            v4h pp[4];
#pragma unroll
            for (int nb = 0; nb < 4; ++nb) {
                v4f acc = (v4f){-SM_OFF2, -SM_OFF2, -SM_OFF2, -SM_OFF2};
                acc = __builtin_amdgcn_mfma_f32_16x16x32_f16(a0, Qf[nb][0], acc, 0, 0, 0);
                acc = __builtin_amdgcn_mfma_f32_16x16x32_f16(a1, Qf[nb][1], acc, 0, 0, 0);
                const v2h lo = pk_exp2_h2(acc[0], acc[1]);
                const v2h hi = pk_exp2_h2(acc[2], acc[3]);
                l_[nb] = __builtin_amdgcn_fdot2(lo, one2, l_[nb], false);
                l_[nb] = __builtin_amdgcn_fdot2(hi, one2, l_[nb], false);
                v4h p;
                p[0] = lo[0]; p[1] = lo[1]; p[2] = hi[0]; p[3] = hi[1];
                pp[nb] = p;
            }
#pragma unroll
            for (int db = 0; db < 4; ++db) {
                v4h a = *(const v4h*)&Vts[cur][db * 16 + l15][m * 16 + grp * 4];
#pragma unroll
                for (int nb = 0; nb < 4; ++nb)
                    O[db][nb] = __builtin_amdgcn_mfma_f32_16x16x16f16(a, pp[nb], O[db][nb], 0, 0, 0);
            }
        }
        __builtin_amdgcn_s_setprio(0);

        // stage tile t+1 (regs -> other LDS buffer); issue loads for tile t+2
        if (t < SEQ / 64 - 1) {
            *(v8h*)&Ks[cur ^ 1][srow][sseg * 16]      = kr0;
            *(v8h*)&Ks[cur ^ 1][srow][sseg * 16 + 8]  = kr1;
            *(v8h*)&Vts[cur ^ 1][srow][sseg * 16]     = vr0;
            *(v8h*)&Vts[cur ^ 1][srow][sseg * 16 + 8] = vr1;
            if (t < SEQ / 64 - 2) {
                const size_t ko = (size_t)(t + 2) * 64 * 64;
                const size_t vo = (size_t)(t + 2) * 64;
                kr0 = *(const v8h*)(kp + ko);
                kr1 = *(const v8h*)(kp + ko + 8);
                vr0 = *(const v8h*)(vp + vo);
                vr1 = *(const v8h*)(vp + vo + 8);
            }
        }
        __syncthreads();
    }

    // epilogue: reduce l over the 4 key-groups (grp), normalize, store fp16
#pragma unroll
    for (int nb = 0; nb < 4; ++nb) {
        float l = l_[nb];
        l += __shfl_xor(l, 16);
        l += __shfl_xor(l, 32);
        const float inv = 1.0f / l;
        const size_t row = (size_t)b * SEQ + qblk * 256 + w * 64 + nb * 16 + l15;
#pragma unroll
        for (int db = 0; db < 4; ++db) {
            v4h o;
            o[0] = (_Float16)(O[db][nb][0] * inv);
            o[1] = (_Float16)(O[db][nb][1] * inv);
            o[2] = (_Float16)(O[db][nb][2] * inv);
            o[3] = (_Float16)(O[db][nb][3] * inv);
            *(v4h*)(out + row * INNER + h * 64 + db * 16 + grp * 4) = o;
        }
    }
}

extern "C" void kernel_launch(void* const* d_in, const int* in_sizes, int n_in,
                              void* d_out, int out_size, void* d_ws, size_t ws_size,
                              hipStream_t stream) {
    const float* x     = (const float*)d_in[0];
    const float* ln_g  = (const float*)d_in[1];
    const float* ln_b  = (const float*)d_in[2];
    const float* w_qkv = (const float*)d_in[3];
    const float* w_out = (const float*)d_in[4];
    const float* b_out = (const float*)d_in[5];
    float* out = (float*)d_out;

    char* ws = (char*)d_ws;
    const size_t MB = 1024 * 1024;
    _Float16* xnh   = (_Float16*)(ws);               // [0,16) MB
    _Float16* W1t   = (_Float16*)(ws + 16 * MB);     // [16,22)
    _Float16* W2t   = (_Float16*)(ws + 22 * MB);     // [22,24)
    float2*   ropet = (float2*)(ws + 24 * MB);       // [24,25)
    _Float16* Qh    = (_Float16*)(ws + 72 * MB);     // [72,88)
    _Float16* Kh    = (_Float16*)(ws + 88 * MB);     // [88,104)
    _Float16* Vtg   = (_Float16*)(ws + 104 * MB);    // [104,120)
    _Float16* attnh = (_Float16*)(ws);               // reuse xnh (dead after fused gemm)

    // one merged preprocessing launch: LN + wcvt(Wqkv) + wcvt(Wout) + rope table
    prep_kernel<<<ROWS + 1024 + 512, 256, 0, stream>>>(
        x, ln_g, ln_b, xnh, w_qkv, W1t, w_out, W2t, ropet);

    gemm_qkv_rope<<<dim3(3 * INNER / 128, ROWS / 128), 256, 0, stream>>>(
        xnh, W1t, ropet, Qh, Kh, Vtg);

    fa_kernel<<<512, 256, 0, stream>>>(Qh, Kh, Vtg, attnh);

    gemm_nt_f<<<dim3(DIM / 64, ROWS / 128), 256, 0, stream>>>(
        attnh, W2t, b_out, out, ROWS, DIM, INNER);
}

// Round 11
// 284.250 us; speedup vs baseline: 1.0473x; 1.0473x over previous
//
#include <hip/hip_runtime.h>
#include <math.h>

#define HEADS 16
#define DIM_HEAD 64
#define DIM 1024
#define INNER 1024
#define SEQ 2048
#define BATCH 4
#define ROWS (BATCH * SEQ)   // 8192

typedef _Float16 v8h __attribute__((ext_vector_type(8)));
typedef _Float16 v4h __attribute__((ext_vector_type(4)));
typedef _Float16 v2h __attribute__((ext_vector_type(2)));
typedef __fp16   v2fp __attribute__((ext_vector_type(2)));
typedef float    v4f __attribute__((ext_vector_type(4)));

static __device__ __forceinline__ v2h pk_exp2_h2(float a, float b) {
    v2fp r = __builtin_amdgcn_cvt_pkrtz(__builtin_amdgcn_exp2f(a),
                                        __builtin_amdgcn_exp2f(b));
    return __builtin_bit_cast(v2h, r);
}

// async global->LDS, 16B per lane; LDS dst is wave-uniform base + lane*16
#define GLOAD_LDS16(gptr, lptr)                                                   \
    __builtin_amdgcn_global_load_lds(                                             \
        (const __attribute__((address_space(1))) void*)(gptr),                    \
        (__attribute__((address_space(3))) void*)(lptr), 16, 0, 0)

// ---------------- merged preprocessing: LN + 2x weight-convert + rope table ----------------
__global__ __launch_bounds__(256) void prep_kernel(const float* __restrict__ x,
                                                   const float* __restrict__ g,
                                                   const float* __restrict__ bvec,
                                                   _Float16* __restrict__ xn,
                                                   const float* __restrict__ w_qkv,
                                                   _Float16* __restrict__ W1t,
                                                   const float* __restrict__ w_out,
                                                   _Float16* __restrict__ W2t,
                                                   float2* __restrict__ tab) {
    __shared__ __align__(16) char pmem[64 * 72 * 2];   // wcvt tile; ln reuses first 2KB
    const int bid = blockIdx.x;
    const int tid = threadIdx.x;

    if (bid < ROWS) {
        // ---- LayerNorm: one block per row, fp16 out ----
        float2* red = (float2*)pmem;
        const float* xr = x + (size_t)bid * DIM;
        float4 v = *(const float4*)(xr + tid * 4);
        float s  = v.x + v.y + v.z + v.w;
        float ss = v.x * v.x + v.y * v.y + v.z * v.z + v.w * v.w;
        red[tid] = make_float2(s, ss);
        __syncthreads();
        for (int off = 128; off > 0; off >>= 1) {
            if (tid < off) {
                red[tid].x += red[tid + off].x;
                red[tid].y += red[tid + off].y;
            }
            __syncthreads();
        }
        const float mu  = red[0].x * (1.0f / DIM);
        const float var = red[0].y * (1.0f / DIM) - mu * mu;
        const float rinv = rsqrtf(var + 1e-5f);
        const int c = tid * 4;
        float4 gg = *(const float4*)(g + c);
        float4 bb = *(const float4*)(bvec + c);
        v4h o;
        o[0] = (_Float16)((v.x - mu) * rinv * gg.x + bb.x);
        o[1] = (_Float16)((v.y - mu) * rinv * gg.y + bb.y);
        o[2] = (_Float16)((v.z - mu) * rinv * gg.z + bb.z);
        o[3] = (_Float16)((v.w - mu) * rinv * gg.w + bb.w);
        *(v4h*)(xn + (size_t)bid * DIM + c) = o;
    } else if (bid < ROWS + 768 + 256) {
        // ---- weight convert + transpose: W[K][N] f32 -> Wt[N][K] fp16 ----
        const float* W; _Float16* Wt; int K, N, j0, i0;
        if (bid < ROWS + 768) {
            const int t = bid - ROWS;            // grid was (48, 16)
            W = w_qkv; Wt = W1t; K = DIM; N = 3 * INNER;
            j0 = (t % 48) * 64; i0 = (t / 48) * 64;
        } else {
            const int t = bid - ROWS - 768;      // grid was (16, 16)
            W = w_out; Wt = W2t; K = INNER; N = DIM;
            j0 = (t % 16) * 64; i0 = (t / 16) * 64;
        }
        _Float16 (*T)[72] = (_Float16(*)[72])pmem;
        const int row = tid >> 2;
        const int cs  = (tid & 3) * 16;
#pragma unroll
        for (int e = 0; e < 16; e += 4) {
            float4 v = *(const float4*)(W + (size_t)(i0 + row) * N + j0 + cs + e);
            T[cs + e + 0][row] = (_Float16)v.x;
            T[cs + e + 1][row] = (_Float16)v.y;
            T[cs + e + 2][row] = (_Float16)v.z;
            T[cs + e + 3][row] = (_Float16)v.w;
        }
        __syncthreads();
        v8h o0 = *(const v8h*)&T[row][cs];
        v8h o1 = *(const v8h*)&T[row][cs + 8];
        *(v8h*)(Wt + (size_t)(j0 + row) * K + i0 + cs) = o0;
        *(v8h*)(Wt + (size_t)(j0 + row) * K + i0 + cs + 8) = o1;
    } else {
        // ---- RoPE cos/sin table: [SEQ][64] of (cos, sin) ----
        const int idx = (bid - (ROWS + 1024)) * 256 + tid;
        const int n = idx >> 6, d = idx & 63;
        const float ang = (float)n * exp2f((float)(d >> 1) * (-13.287712379549449f / 32.0f));
        float s, c;
        sincosf(ang, &s, &c);
        tab[idx] = make_float2(c, s);
    }
}

// ---------------- fused QKV GEMM + RoPE + repack (round-7 version, best-known) ----------------
// BK=64, XOR-swizzled LDS, single-buffer vmcnt-drain loop.
#define QSCALE 0.18033688011112042f  /* log2(e)/8 */
__global__ __launch_bounds__(256) void gemm_qkv_rope(const _Float16* __restrict__ A,
                                                     const _Float16* __restrict__ Bt,
                                                     const float2* __restrict__ tab,
                                                     _Float16* __restrict__ Qh,
                                                     _Float16* __restrict__ Kh,
                                                     _Float16* __restrict__ Vtg) {
    const int N = 3 * INNER, K = DIM;
    // union: main loop uses As/Bs (32 KB); Q/K epilogue reuses as Ts (34 KB)
    __shared__ __align__(16) char smem[34816];
    _Float16* As = (_Float16*)smem;             // [128][64] halves, swizzled slots
    _Float16* Bs = (_Float16*)(smem + 16384);   // [128][64]
    _Float16* Ts = (_Float16*)smem;             // [4][64][68] epilogue transpose

    const int tid = threadIdx.x;
    const int w = tid >> 6, lane = tid & 63;
    const int l15 = lane & 15, grp = lane >> 4;
    const int wm = w >> 1, wn = w & 1;
    const int m0 = blockIdx.y * 128, n0 = blockIdx.x * 128;

    const int srow7 = (tid >> 3) & 7;           // row&7 for the staged row
    const int sslot = (tid & 7) ^ srow7;        // swizzled source slot

    v4f acc[4][4];
#pragma unroll
    for (int i = 0; i < 4; ++i)
#pragma unroll
        for (int j = 0; j < 4; ++j) acc[i][j] = (v4f){0.f, 0.f, 0.f, 0.f};

    for (int k0 = 0; k0 < K; k0 += 64) {
#pragma unroll
        for (int q = 0; q < 4; ++q) {
            const int row = q * 32 + (tid >> 3);
            GLOAD_LDS16(A  + (size_t)(m0 + row) * K + k0 + sslot * 8, As + q * 2048 + tid * 8);
            GLOAD_LDS16(Bt + (size_t)(n0 + row) * K + k0 + sslot * 8, Bs + q * 2048 + tid * 8);
        }
        __syncthreads();

#pragma unroll
        for (int ks = 0; ks < 2; ++ks) {
            const int sl = ((ks * 4 + grp) ^ (l15 & 7)) * 8;  // swizzled col (halves)
            v8h a[4], bf[4];
#pragma unroll
            for (int i = 0; i < 4; ++i) {
                a[i]  = *(const v8h*)(As + (size_t)(wm * 64 + i * 16 + l15) * 64 + sl);
                bf[i] = *(const v8h*)(Bs + (size_t)(wn * 64 + i * 16 + l15) * 64 + sl);
            }
#pragma unroll
            for (int mb = 0; mb < 4; ++mb)
#pragma unroll
                for (int nb = 0; nb < 4; ++nb)
                    acc[mb][nb] = __builtin_amdgcn_mfma_f32_16x16x32_f16(a[mb], bf[nb], acc[mb][nb], 0, 0, 0);
        }
        __syncthreads();
    }

    const int mrow = m0 + wm * 64;       // token-row base (64-aligned)
    const int ncol = n0 + wn * 64;       // qkv-col base (one head section)
    const int sec   = ncol >> 10;        // 0=q, 1=k, 2=v (block-uniform)
    const int h     = (ncol >> 6) & 15;
    const int b     = mrow >> 11;
    const int nbase = mrow & (SEQ - 1);
    const int bh    = b * 16 + h;

    if (sec == 2) {
        // V: transposed store Vtg[bh][d][n], 4 consecutive n per 8B store
#pragma unroll
        for (int nb = 0; nb < 4; ++nb) {
            const int d = nb * 16 + l15;
            _Float16* vdst = Vtg + ((size_t)bh * 64 + d) * SEQ;
#pragma unroll
            for (int mb = 0; mb < 4; ++mb) {
                const int n = nbase + mb * 16 + grp * 4;
                v4h o;
                o[0] = (_Float16)acc[mb][nb][0];
                o[1] = (_Float16)acc[mb][nb][1];
                o[2] = (_Float16)acc[mb][nb][2];
                o[3] = (_Float16)acc[mb][nb][3];
                *(v4h*)(vdst + n) = o;
            }
        }
    } else {
        _Float16* dst  = (sec == 0) ? Qh : Kh;
        const float qs = (sec == 0) ? QSCALE : 1.0f;
        _Float16* Tw = Ts + (size_t)w * (64 * 68);
        // rope in-register, land in per-wave LDS tile [n_local][d]
#pragma unroll
        for (int mb = 0; mb < 4; ++mb) {
#pragma unroll
            for (int r = 0; r < 4; ++r) {
                const int nl = mb * 16 + grp * 4 + r;
                const float2* tn = tab + (((size_t)(nbase + nl)) << 6);
#pragma unroll
                for (int nb = 0; nb < 4; ++nb) {
                    const int d = nb * 16 + l15;
                    const float2 cs = tn[d];
                    const float partner = acc[mb][nb ^ 2][r];
                    const float sg = (nb < 2) ? -cs.y : cs.y;
                    Tw[nl * 68 + d] = (_Float16)((acc[mb][nb][r] * cs.x + partner * sg) * qs);
                }
            }
        }
        __syncthreads();
        // coalesced 128B-row stores: 4 passes x (16 rows, 32B per lane)
#pragma unroll
        for (int p = 0; p < 4; ++p) {
            const int rr = p * 16 + (lane >> 2);
            const int cc = (lane & 3) * 16;
            v8h x0 = *(const v8h*)&Tw[rr * 68 + cc];
            v8h x1 = *(const v8h*)&Tw[rr * 68 + cc + 8];
            _Float16* gd = dst + ((size_t)bh * SEQ + nbase + rr) * 64 + cc;
            *(v8h*)gd = x0;
            *(v8h*)(gd + 8) = x1;
        }
    }
}

// ---------------- output-projection GEMM: fp32 out + bias ----------------
// REVERTED to the 128x128 tile (round-10's 128x64 retile cost ~15us: doubled
// A-panel re-reads, halved MFMA-per-LDS-read). One delta vs round 8: the
// round-7-proven BK=64 + XOR-swizzle treatment (half the barrier/drain events,
// conflict-free b128 fragment reads). Grid (8,64)=512 blocks, LDS 32KB.
__global__ __launch_bounds__(256) void gemm_nt_f(const _Float16* __restrict__ A,
                                                 const _Float16* __restrict__ Bt,
                                                 const float* __restrict__ bias,
                                                 float* __restrict__ C,
                                                 int M, int N, int K) {
    __shared__ __align__(16) _Float16 As[128 * 64];   // 16 KB
    __shared__ __align__(16) _Float16 Bs[128 * 64];   // 16 KB
    const int tid = threadIdx.x;
    const int w = tid >> 6, lane = tid & 63;
    const int l15 = lane & 15, grp = lane >> 4;
    const int wm = w >> 1, wn = w & 1;
    const int m0 = blockIdx.y * 128, n0 = blockIdx.x * 128;

    const int srow7 = (tid >> 3) & 7;           // row&7 for the staged row
    const int sslot = (tid & 7) ^ srow7;        // swizzled source 16B slot

    v4f acc[4][4];
#pragma unroll
    for (int i = 0; i < 4; ++i)
#pragma unroll
        for (int j = 0; j < 4; ++j) acc[i][j] = (v4f){0.f, 0.f, 0.f, 0.f};

    for (int k0 = 0; k0 < K; k0 += 64) {
#pragma unroll
        for (int q = 0; q < 4; ++q) {
            const int row = q * 32 + (tid >> 3);
            GLOAD_LDS16(A  + (size_t)(m0 + row) * K + k0 + sslot * 8, As + q * 2048 + tid * 8);
            GLOAD_LDS16(Bt + (size_t)(n0 + row) * K + k0 + sslot * 8, Bs + q * 2048 + tid * 8);
        }
        __syncthreads();

#pragma unroll
        for (int ks = 0; ks < 2; ++ks) {
            const int sl = ((ks * 4 + grp) ^ (l15 & 7)) * 8;  // swizzled col (halves)
            v8h a[4], bf[4];
#pragma unroll
            for (int i = 0; i < 4; ++i) {
                a[i]  = *(const v8h*)(As + (size_t)(wm * 64 + i * 16 + l15) * 64 + sl);
                bf[i] = *(const v8h*)(Bs + (size_t)(wn * 64 + i * 16 + l15) * 64 + sl);
            }
#pragma unroll
            for (int mb = 0; mb < 4; ++mb)
#pragma unroll
                for (int nb = 0; nb < 4; ++nb)
                    acc[mb][nb] = __builtin_amdgcn_mfma_f32_16x16x32_f16(a[mb], bf[nb], acc[mb][nb], 0, 0, 0);
        }
        __syncthreads();
    }

    const int mrow = m0 + wm * 64;
    const int ncol = n0 + wn * 64;
#pragma unroll
    for (int nb = 0; nb < 4; ++nb) {
        const float bs = bias[ncol + nb * 16 + l15];
#pragma unroll
        for (int mb = 0; mb < 4; ++mb)
#pragma unroll
            for (int r = 0; r < 4; ++r)
                C[(size_t)(mrow + mb * 16 + grp * 4 + r) * N + ncol + nb * 16 + l15] =
                    acc[mb][nb][r] + bs;
    }
}

// ---------------- MFMA flash attention: 64 queries/wave, 256/block (UNCHANGED control) ----------------
#define SM_OFF2 7.2134752044448170f  /* 5 * log2(e) */
__global__ __launch_bounds__(256, 2) void fa_kernel(const _Float16* __restrict__ Qh,
                                                    const _Float16* __restrict__ Kh,
                                                    const _Float16* __restrict__ Vtg,
                                                    _Float16* __restrict__ out) {
    const int i = blockIdx.x;                 // 512 blocks
    const int bh = (i & 7) + ((i >> 6) << 3); // head bh -> XCD bh%8
    const int qblk = (i >> 3) & 7;            // 8 q-blocks of 256
    const int b = bh >> 4, h = bh & 15;
    const int tid = threadIdx.x;
    const int w = tid >> 6;
    const int lane = tid & 63;
    const int l15 = lane & 15;
    const int grp = lane >> 4;

    __shared__ _Float16 Ks[2][64][68];
    __shared__ _Float16 Vts[2][64][68];

    // Q fragments: wave w owns queries [qblk*256 + w*64, +64)
    v8h Qf[4][2];
    const _Float16* Qbase = Qh + ((size_t)bh * SEQ + qblk * 256 + w * 64) * 64;
#pragma unroll
    for (int nb = 0; nb < 4; ++nb)
#pragma unroll
        for (int ks = 0; ks < 2; ++ks)
            Qf[nb][ks] = *(const v8h*)(Qbase + (size_t)(nb * 16 + l15) * 64 + ks * 32 + grp * 8);

    float l_[4] = {0.f, 0.f, 0.f, 0.f};
    v4f O[4][4];
#pragma unroll
    for (int db = 0; db < 4; ++db)
#pragma unroll
        for (int nb = 0; nb < 4; ++nb) O[db][nb] = (v4f){0.f, 0.f, 0.f, 0.f};

    const int srow = tid >> 2;
    const int sseg = tid & 3;
    const _Float16* kp = Kh + (size_t)bh * SEQ * 64 + (size_t)srow * 64 + sseg * 16;
    const _Float16* vp = Vtg + (size_t)bh * 64 * SEQ + (size_t)srow * SEQ + sseg * 16;

    const v2h one2 = {(_Float16)1.0f, (_Float16)1.0f};

    // prologue: tile 0 -> LDS buf0; issue tile 1 -> regs
    v8h kr0 = *(const v8h*)(kp);
    v8h kr1 = *(const v8h*)(kp + 8);
    v8h vr0 = *(const v8h*)(vp);
    v8h vr1 = *(const v8h*)(vp + 8);
    *(v8h*)&Ks[0][srow][sseg * 16]      = kr0;
    *(v8h*)&Ks[0][srow][sseg * 16 + 8]  = kr1;
    *(v8h*)&Vts[0][srow][sseg * 16]     = vr0;
    *(v8h*)&Vts[0][srow][sseg * 16 + 8] = vr1;
    __syncthreads();
    kr0 = *(const v8h*)(kp + 64 * 64);
    kr1 = *(const v8h*)(kp + 64 * 64 + 8);
    vr0 = *(const v8h*)(vp + 64);
    vr1 = *(const v8h*)(vp + 64 + 8);

    for (int t = 0; t < SEQ / 64; ++t) {
        const int cur = t & 1;

        __builtin_amdgcn_s_setprio(1);
#pragma unroll
        for (int m = 0; m < 4; ++m) {
            v8h a0 = *(const v8h*)&Ks[cur][m * 16 + l15][grp * 8];
            v8h a1 = *(const v8h*)&Ks[cur][m * 16 + l15][32 + grp * 8];
            v4h pp[4];
#pragma unroll
            for (int nb = 0; nb < 4; ++nb) {
                v4f acc = (v4f){-SM_OFF2, -SM_OFF2, -SM_OFF2, -SM_OFF2};
                acc = __builtin_amdgcn_mfma_f32_16x16x32_f16(a0, Qf[nb][0], acc, 0, 0, 0);
                acc = __builtin_amdgcn_mfma_f32_16x16x32_f16(a1, Qf[nb][1], acc, 0, 0, 0);
                const v2h lo = pk_exp2_h2(acc[0], acc[1]);
                const v2h hi = pk_exp2_h2(acc[2], acc[3]);
                l_[nb] = __builtin_amdgcn_fdot2(lo, one2, l_[nb], false);
                l_[nb] = __builtin_amdgcn_fdot2(hi, one2, l_[nb], false);
                v4h p;
                p[0] = lo[0]; p[1] = lo[1]; p[2] = hi[0]; p[3] = hi[1];
                pp[nb] = p;
            }
#pragma unroll
            for (int db = 0; db < 4; ++db) {
                v4h a = *(const v4h*)&Vts[cur][db * 16 + l15][m * 16 + grp * 4];
#pragma unroll
                for (int nb = 0; nb < 4; ++nb)
                    O[db][nb] = __builtin_amdgcn_mfma_f32_16x16x16f16(a, pp[nb], O[db][nb], 0, 0, 0);
            }
        }
        __builtin_amdgcn_s_setprio(0);

        // stage tile t+1 (regs -> other LDS buffer); issue loads for tile t+2
        if (t < SEQ / 64 - 1) {
            *(v8h*)&Ks[cur ^ 1][srow][sseg * 16]      = kr0;
            *(v8h*)&Ks[cur ^ 1][srow][sseg * 16 + 8]  = kr1;
            *(v8h*)&Vts[cur ^ 1][srow][sseg * 16]     = vr0;
            *(v8h*)&Vts[cur ^ 1][srow][sseg * 16 + 8] = vr1;
            if (t < SEQ / 64 - 2) {
                const size_t ko = (size_t)(t + 2) * 64 * 64;
                const size_t vo = (size_t)(t + 2) * 64;
                kr0 = *(const v8h*)(kp + ko);
                kr1 = *(const v8h*)(kp + ko + 8);
                vr0 = *(const v8h*)(vp + vo);
                vr1 = *(const v8h*)(vp + vo + 8);
            }
        }
        __syncthreads();
    }

    // epilogue: reduce l over the 4 key-groups (grp), normalize, store fp16
#pragma unroll
    for (int nb = 0; nb < 4; ++nb) {
        float l = l_[nb];
        l += __shfl_xor(l, 16);
        l += __shfl_xor(l, 32);
        const float inv = 1.0f / l;
        const size_t row = (size_t)b * SEQ + qblk * 256 + w * 64 + nb * 16 + l15;
#pragma unroll
        for (int db = 0; db < 4; ++db) {
            v4h o;
            o[0] = (_Float16)(O[db][nb][0] * inv);
            o[1] = (_Float16)(O[db][nb][1] * inv);
            o[2] = (_Float16)(O[db][nb][2] * inv);
            o[3] = (_Float16)(O[db][nb][3] * inv);
            *(v4h*)(out + row * INNER + h * 64 + db * 16 + grp * 4) = o;
        }
    }
}

extern "C" void kernel_launch(void* const* d_in, const int* in_sizes, int n_in,
                              void* d_out, int out_size, void* d_ws, size_t ws_size,
                              hipStream_t stream) {
    const float* x     = (const float*)d_in[0];
    const float* ln_g  = (const float*)d_in[1];
    const float* ln_b  = (const float*)d_in[2];
    const float* w_qkv = (const float*)d_in[3];
    const float* w_out = (const float*)d_in[4];
    const float* b_out = (const float*)d_in[5];
    float* out = (float*)d_out;

    char* ws = (char*)d_ws;
    const size_t MB = 1024 * 1024;
    _Float16* xnh   = (_Float16*)(ws);               // [0,16) MB
    _Float16* W1t   = (_Float16*)(ws + 16 * MB);     // [16,22)
    _Float16* W2t   = (_Float16*)(ws + 22 * MB);     // [22,24)
    float2*   ropet = (float2*)(ws + 24 * MB);       // [24,25)
    _Float16* Qh    = (_Float16*)(ws + 72 * MB);     // [72,88)
    _Float16* Kh    = (_Float16*)(ws + 88 * MB);     // [88,104)
    _Float16* Vtg   = (_Float16*)(ws + 104 * MB);    // [104,120)
    _Float16* attnh = (_Float16*)(ws);               // reuse xnh (dead after fused gemm)

    // one merged preprocessing launch: LN + wcvt(Wqkv) + wcvt(Wout) + rope table
    prep_kernel<<<ROWS + 1024 + 512, 256, 0, stream>>>(
        x, ln_g, ln_b, xnh, w_qkv, W1t, w_out, W2t, ropet);

    gemm_qkv_rope<<<dim3(3 * INNER / 128, ROWS / 128), 256, 0, stream>>>(
        xnh, W1t, ropet, Qh, Kh, Vtg);

    fa_kernel<<<512, 256, 0, stream>>>(Qh, Kh, Vtg, attnh);

    gemm_nt_f<<<dim3(DIM / 128, ROWS / 128), 256, 0, stream>>>(
        attnh, W2t, b_out, out, ROWS, DIM, INNER);
}

// Round 12
// 271.418 us; speedup vs baseline: 1.0968x; 1.0473x over previous
//
#include <hip/hip_runtime.h>
#include <math.h>

#define HEADS 16
#define DIM_HEAD 64
#define DIM 1024
#define INNER 1024
#define SEQ 2048
#define BATCH 4
#define ROWS (BATCH * SEQ)   // 8192

typedef _Float16 v8h __attribute__((ext_vector_type(8)));
typedef _Float16 v4h __attribute__((ext_vector_type(4)));
typedef _Float16 v2h __attribute__((ext_vector_type(2)));
typedef __fp16   v2fp __attribute__((ext_vector_type(2)));
typedef float    v4f __attribute__((ext_vector_type(4)));

static __device__ __forceinline__ v2h pk_exp2_h2(float a, float b) {
    v2fp r = __builtin_amdgcn_cvt_pkrtz(__builtin_amdgcn_exp2f(a),
                                        __builtin_amdgcn_exp2f(b));
    return __builtin_bit_cast(v2h, r);
}

// async global->LDS, 16B per lane; LDS dst is wave-uniform base + lane*16
#define GLOAD_LDS16(gptr, lptr)                                                   \
    __builtin_amdgcn_global_load_lds(                                             \
        (const __attribute__((address_space(1))) void*)(gptr),                    \
        (__attribute__((address_space(3))) void*)(lptr), 16, 0, 0)

// ---------------- merged preprocessing: LN + 2x weight-convert + rope table ----------------
__global__ __launch_bounds__(256) void prep_kernel(const float* __restrict__ x,
                                                   const float* __restrict__ g,
                                                   const float* __restrict__ bvec,
                                                   _Float16* __restrict__ xn,
                                                   const float* __restrict__ w_qkv,
                                                   _Float16* __restrict__ W1t,
                                                   const float* __restrict__ w_out,
                                                   _Float16* __restrict__ W2t,
                                                   float2* __restrict__ tab) {
    __shared__ __align__(16) char pmem[64 * 72 * 2];   // wcvt tile; ln reuses first 2KB
    const int bid = blockIdx.x;
    const int tid = threadIdx.x;

    if (bid < ROWS) {
        // ---- LayerNorm: one block per row, fp16 out ----
        float2* red = (float2*)pmem;
        const float* xr = x + (size_t)bid * DIM;
        float4 v = *(const float4*)(xr + tid * 4);
        float s  = v.x + v.y + v.z + v.w;
        float ss = v.x * v.x + v.y * v.y + v.z * v.z + v.w * v.w;
        red[tid] = make_float2(s, ss);
        __syncthreads();
        for (int off = 128; off > 0; off >>= 1) {
            if (tid < off) {
                red[tid].x += red[tid + off].x;
                red[tid].y += red[tid + off].y;
            }
            __syncthreads();
        }
        const float mu  = red[0].x * (1.0f / DIM);
        const float var = red[0].y * (1.0f / DIM) - mu * mu;
        const float rinv = rsqrtf(var + 1e-5f);
        const int c = tid * 4;
        float4 gg = *(const float4*)(g + c);
        float4 bb = *(const float4*)(bvec + c);
        v4h o;
        o[0] = (_Float16)((v.x - mu) * rinv * gg.x + bb.x);
        o[1] = (_Float16)((v.y - mu) * rinv * gg.y + bb.y);
        o[2] = (_Float16)((v.z - mu) * rinv * gg.z + bb.z);
        o[3] = (_Float16)((v.w - mu) * rinv * gg.w + bb.w);
        *(v4h*)(xn + (size_t)bid * DIM + c) = o;
    } else if (bid < ROWS + 768 + 256) {
        // ---- weight convert + transpose: W[K][N] f32 -> Wt[N][K] fp16 ----
        const float* W; _Float16* Wt; int K, N, j0, i0;
        if (bid < ROWS + 768) {
            const int t = bid - ROWS;            // grid was (48, 16)
            W = w_qkv; Wt = W1t; K = DIM; N = 3 * INNER;
            j0 = (t % 48) * 64; i0 = (t / 48) * 64;
        } else {
            const int t = bid - ROWS - 768;      // grid was (16, 16)
            W = w_out; Wt = W2t; K = INNER; N = DIM;
            j0 = (t % 16) * 64; i0 = (t / 16) * 64;
        }
        _Float16 (*T)[72] = (_Float16(*)[72])pmem;
        const int row = tid >> 2;
        const int cs  = (tid & 3) * 16;
#pragma unroll
        for (int e = 0; e < 16; e += 4) {
            float4 v = *(const float4*)(W + (size_t)(i0 + row) * N + j0 + cs + e);
            T[cs + e + 0][row] = (_Float16)v.x;
            T[cs + e + 1][row] = (_Float16)v.y;
            T[cs + e + 2][row] = (_Float16)v.z;
            T[cs + e + 3][row] = (_Float16)v.w;
        }
        __syncthreads();
        v8h o0 = *(const v8h*)&T[row][cs];
        v8h o1 = *(const v8h*)&T[row][cs + 8];
        *(v8h*)(Wt + (size_t)(j0 + row) * K + i0 + cs) = o0;
        *(v8h*)(Wt + (size_t)(j0 + row) * K + i0 + cs + 8) = o1;
    } else {
        // ---- RoPE cos/sin table: [SEQ][64] of (cos, sin) ----
        const int idx = (bid - (ROWS + 1024)) * 256 + tid;
        const int n = idx >> 6, d = idx & 63;
        const float ang = (float)n * exp2f((float)(d >> 1) * (-13.287712379549449f / 32.0f));
        float s, c;
        sincosf(ang, &s, &c);
        tab[idx] = make_float2(c, s);
    }
}

// ---------------- fused QKV GEMM + RoPE + repack (round-7 version, best-known) ----------------
// BK=64, XOR-swizzled LDS, single-buffer vmcnt-drain loop.
#define QSCALE 0.18033688011112042f  /* log2(e)/8 */
__global__ __launch_bounds__(256) void gemm_qkv_rope(const _Float16* __restrict__ A,
                                                     const _Float16* __restrict__ Bt,
                                                     const float2* __restrict__ tab,
                                                     _Float16* __restrict__ Qh,
                                                     _Float16* __restrict__ Kh,
                                                     _Float16* __restrict__ Vtg) {
    const int N = 3 * INNER, K = DIM;
    // union: main loop uses As/Bs (32 KB); Q/K epilogue reuses as Ts (34 KB)
    __shared__ __align__(16) char smem[34816];
    _Float16* As = (_Float16*)smem;             // [128][64] halves, swizzled slots
    _Float16* Bs = (_Float16*)(smem + 16384);   // [128][64]
    _Float16* Ts = (_Float16*)smem;             // [4][64][68] epilogue transpose

    const int tid = threadIdx.x;
    const int w = tid >> 6, lane = tid & 63;
    const int l15 = lane & 15, grp = lane >> 4;
    const int wm = w >> 1, wn = w & 1;
    const int m0 = blockIdx.y * 128, n0 = blockIdx.x * 128;

    const int srow7 = (tid >> 3) & 7;           // row&7 for the staged row
    const int sslot = (tid & 7) ^ srow7;        // swizzled source slot

    v4f acc[4][4];
#pragma unroll
    for (int i = 0; i < 4; ++i)
#pragma unroll
        for (int j = 0; j < 4; ++j) acc[i][j] = (v4f){0.f, 0.f, 0.f, 0.f};

    for (int k0 = 0; k0 < K; k0 += 64) {
#pragma unroll
        for (int q = 0; q < 4; ++q) {
            const int row = q * 32 + (tid >> 3);
            GLOAD_LDS16(A  + (size_t)(m0 + row) * K + k0 + sslot * 8, As + q * 2048 + tid * 8);
            GLOAD_LDS16(Bt + (size_t)(n0 + row) * K + k0 + sslot * 8, Bs + q * 2048 + tid * 8);
        }
        __syncthreads();

#pragma unroll
        for (int ks = 0; ks < 2; ++ks) {
            const int sl = ((ks * 4 + grp) ^ (l15 & 7)) * 8;  // swizzled col (halves)
            v8h a[4], bf[4];
#pragma unroll
            for (int i = 0; i < 4; ++i) {
                a[i]  = *(const v8h*)(As + (size_t)(wm * 64 + i * 16 + l15) * 64 + sl);
                bf[i] = *(const v8h*)(Bs + (size_t)(wn * 64 + i * 16 + l15) * 64 + sl);
            }
#pragma unroll
            for (int mb = 0; mb < 4; ++mb)
#pragma unroll
                for (int nb = 0; nb < 4; ++nb)
                    acc[mb][nb] = __builtin_amdgcn_mfma_f32_16x16x32_f16(a[mb], bf[nb], acc[mb][nb], 0, 0, 0);
        }
        __syncthreads();
    }

    const int mrow = m0 + wm * 64;       // token-row base (64-aligned)
    const int ncol = n0 + wn * 64;       // qkv-col base (one head section)
    const int sec   = ncol >> 10;        // 0=q, 1=k, 2=v (block-uniform)
    const int h     = (ncol >> 6) & 15;
    const int b     = mrow >> 11;
    const int nbase = mrow & (SEQ - 1);
    const int bh    = b * 16 + h;

    if (sec == 2) {
        // V: transposed store Vtg[bh][d][n], 4 consecutive n per 8B store
#pragma unroll
        for (int nb = 0; nb < 4; ++nb) {
            const int d = nb * 16 + l15;
            _Float16* vdst = Vtg + ((size_t)bh * 64 + d) * SEQ;
#pragma unroll
            for (int mb = 0; mb < 4; ++mb) {
                const int n = nbase + mb * 16 + grp * 4;
                v4h o;
                o[0] = (_Float16)acc[mb][nb][0];
                o[1] = (_Float16)acc[mb][nb][1];
                o[2] = (_Float16)acc[mb][nb][2];
                o[3] = (_Float16)acc[mb][nb][3];
                *(v4h*)(vdst + n) = o;
            }
        }
    } else {
        _Float16* dst  = (sec == 0) ? Qh : Kh;
        const float qs = (sec == 0) ? QSCALE : 1.0f;
        _Float16* Tw = Ts + (size_t)w * (64 * 68);
        // rope in-register, land in per-wave LDS tile [n_local][d]
#pragma unroll
        for (int mb = 0; mb < 4; ++mb) {
#pragma unroll
            for (int r = 0; r < 4; ++r) {
                const int nl = mb * 16 + grp * 4 + r;
                const float2* tn = tab + (((size_t)(nbase + nl)) << 6);
#pragma unroll
                for (int nb = 0; nb < 4; ++nb) {
                    const int d = nb * 16 + l15;
                    const float2 cs = tn[d];
                    const float partner = acc[mb][nb ^ 2][r];
                    const float sg = (nb < 2) ? -cs.y : cs.y;
                    Tw[nl * 68 + d] = (_Float16)((acc[mb][nb][r] * cs.x + partner * sg) * qs);
                }
            }
        }
        __syncthreads();
        // coalesced 128B-row stores: 4 passes x (16 rows, 32B per lane)
#pragma unroll
        for (int p = 0; p < 4; ++p) {
            const int rr = p * 16 + (lane >> 2);
            const int cc = (lane & 3) * 16;
            v8h x0 = *(const v8h*)&Tw[rr * 68 + cc];
            v8h x1 = *(const v8h*)&Tw[rr * 68 + cc + 8];
            _Float16* gd = dst + ((size_t)bh * SEQ + nbase + rr) * 64 + cc;
            *(v8h*)gd = x0;
            *(v8h*)(gd + 8) = x1;
        }
    }
}

// ---------------- output-projection GEMM: fp32 out + bias (round-11 version) ----------------
__global__ __launch_bounds__(256) void gemm_nt_f(const _Float16* __restrict__ A,
                                                 const _Float16* __restrict__ Bt,
                                                 const float* __restrict__ bias,
                                                 float* __restrict__ C,
                                                 int M, int N, int K) {
    __shared__ __align__(16) _Float16 As[128 * 64];   // 16 KB
    __shared__ __align__(16) _Float16 Bs[128 * 64];   // 16 KB
    const int tid = threadIdx.x;
    const int w = tid >> 6, lane = tid & 63;
    const int l15 = lane & 15, grp = lane >> 4;
    const int wm = w >> 1, wn = w & 1;
    const int m0 = blockIdx.y * 128, n0 = blockIdx.x * 128;

    const int srow7 = (tid >> 3) & 7;           // row&7 for the staged row
    const int sslot = (tid & 7) ^ srow7;        // swizzled source 16B slot

    v4f acc[4][4];
#pragma unroll
    for (int i = 0; i < 4; ++i)
#pragma unroll
        for (int j = 0; j < 4; ++j) acc[i][j] = (v4f){0.f, 0.f, 0.f, 0.f};

    for (int k0 = 0; k0 < K; k0 += 64) {
#pragma unroll
        for (int q = 0; q < 4; ++q) {
            const int row = q * 32 + (tid >> 3);
            GLOAD_LDS16(A  + (size_t)(m0 + row) * K + k0 + sslot * 8, As + q * 2048 + tid * 8);
            GLOAD_LDS16(Bt + (size_t)(n0 + row) * K + k0 + sslot * 8, Bs + q * 2048 + tid * 8);
        }
        __syncthreads();

#pragma unroll
        for (int ks = 0; ks < 2; ++ks) {
            const int sl = ((ks * 4 + grp) ^ (l15 & 7)) * 8;  // swizzled col (halves)
            v8h a[4], bf[4];
#pragma unroll
            for (int i = 0; i < 4; ++i) {
                a[i]  = *(const v8h*)(As + (size_t)(wm * 64 + i * 16 + l15) * 64 + sl);
                bf[i] = *(const v8h*)(Bs + (size_t)(wn * 64 + i * 16 + l15) * 64 + sl);
            }
#pragma unroll
            for (int mb = 0; mb < 4; ++mb)
#pragma unroll
                for (int nb = 0; nb < 4; ++nb)
                    acc[mb][nb] = __builtin_amdgcn_mfma_f32_16x16x32_f16(a[mb], bf[nb], acc[mb][nb], 0, 0, 0);
        }
        __syncthreads();
    }

    const int mrow = m0 + wm * 64;
    const int ncol = n0 + wn * 64;
#pragma unroll
    for (int nb = 0; nb < 4; ++nb) {
        const float bs = bias[ncol + nb * 16 + l15];
#pragma unroll
        for (int mb = 0; mb < 4; ++mb)
#pragma unroll
            for (int r = 0; r < 4; ++r)
                C[(size_t)(mrow + mb * 16 + grp * 4 + r) * N + ncol + nb * 16 + l15] =
                    acc[mb][nb][r] + bs;
    }
}

// ---------------- MFMA flash attention: 64 queries/wave, K=32 PV via permuted QK rows ----
// 512 blocks (2/CU); XCD swizzle. This revision: PV upgraded from 64x 16x16x16 to
// 32x 16x16x32 MFMAs per tile/wave (gfx950's 2xK shapes deliver 2x FLOPs at the same
// per-instruction cost; PV at K=16 wasted half the matrix pipe). Zero-shuffle trick:
// the QK A-operand reads K-rows in permuted order row = t2*32 + 8*(l15>>2)+(l15&3)
// + 4*half, so that lane (grp,l15)'s accumulator C-rows are keys t2*32+8grp+4half+r
// and concat(pp[0][nb], pp[1][nb]) is EXACTLY the K=32 B-fragment (keys 8grp..+7).
// V reads stay natural-order b128 (2-way, free). l-sum/epilogue are permutation-
// invariant. Per-tile MFMA issue: 96 -> 64 (-33%).
#define SM_OFF2 7.2134752044448170f  /* 5 * log2(e) */
__global__ __launch_bounds__(256, 2) void fa_kernel(const _Float16* __restrict__ Qh,
                                                    const _Float16* __restrict__ Kh,
                                                    const _Float16* __restrict__ Vtg,
                                                    _Float16* __restrict__ out) {
    const int i = blockIdx.x;                 // 512 blocks
    const int bh = (i & 7) + ((i >> 6) << 3); // head bh -> XCD bh%8
    const int qblk = (i >> 3) & 7;            // 8 q-blocks of 256
    const int b = bh >> 4, h = bh & 15;
    const int tid = threadIdx.x;
    const int w = tid >> 6;
    const int lane = tid & 63;
    const int l15 = lane & 15;
    const int grp = lane >> 4;
    const int kperm = 8 * (l15 >> 2) + (l15 & 3);   // permuted K-row base

    __shared__ _Float16 Ks[2][64][68];
    __shared__ _Float16 Vts[2][64][68];

    // Q fragments: wave w owns queries [qblk*256 + w*64, +64)
    v8h Qf[4][2];
    const _Float16* Qbase = Qh + ((size_t)bh * SEQ + qblk * 256 + w * 64) * 64;
#pragma unroll
    for (int nb = 0; nb < 4; ++nb)
#pragma unroll
        for (int ks = 0; ks < 2; ++ks)
            Qf[nb][ks] = *(const v8h*)(Qbase + (size_t)(nb * 16 + l15) * 64 + ks * 32 + grp * 8);

    float l_[4] = {0.f, 0.f, 0.f, 0.f};
    v4f O[4][4];
#pragma unroll
    for (int db = 0; db < 4; ++db)
#pragma unroll
        for (int nb = 0; nb < 4; ++nb) O[db][nb] = (v4f){0.f, 0.f, 0.f, 0.f};

    const int srow = tid >> 2;
    const int sseg = tid & 3;
    const _Float16* kp = Kh + (size_t)bh * SEQ * 64 + (size_t)srow * 64 + sseg * 16;
    const _Float16* vp = Vtg + (size_t)bh * 64 * SEQ + (size_t)srow * SEQ + sseg * 16;

    const v2h one2 = {(_Float16)1.0f, (_Float16)1.0f};

    // prologue: tile 0 -> LDS buf0; issue tile 1 -> regs
    v8h kr0 = *(const v8h*)(kp);
    v8h kr1 = *(const v8h*)(kp + 8);
    v8h vr0 = *(const v8h*)(vp);
    v8h vr1 = *(const v8h*)(vp + 8);
    *(v8h*)&Ks[0][srow][sseg * 16]      = kr0;
    *(v8h*)&Ks[0][srow][sseg * 16 + 8]  = kr1;
    *(v8h*)&Vts[0][srow][sseg * 16]     = vr0;
    *(v8h*)&Vts[0][srow][sseg * 16 + 8] = vr1;
    __syncthreads();
    kr0 = *(const v8h*)(kp + 64 * 64);
    kr1 = *(const v8h*)(kp + 64 * 64 + 8);
    vr0 = *(const v8h*)(vp + 64);
    vr1 = *(const v8h*)(vp + 64 + 8);

    for (int t = 0; t < SEQ / 64; ++t) {
        const int cur = t & 1;

        __builtin_amdgcn_s_setprio(1);
#pragma unroll
        for (int t2 = 0; t2 < 2; ++t2) {        // 32-key group
            v4h pp[2][4];
#pragma unroll
            for (int half = 0; half < 2; ++half) {
                const int row = t2 * 32 + kperm + half * 4;   // permuted key row
                v8h a0 = *(const v8h*)&Ks[cur][row][grp * 8];
                v8h a1 = *(const v8h*)&Ks[cur][row][32 + grp * 8];
#pragma unroll
                for (int nb = 0; nb < 4; ++nb) {
                    v4f acc = (v4f){-SM_OFF2, -SM_OFF2, -SM_OFF2, -SM_OFF2};
                    acc = __builtin_amdgcn_mfma_f32_16x16x32_f16(a0, Qf[nb][0], acc, 0, 0, 0);
                    acc = __builtin_amdgcn_mfma_f32_16x16x32_f16(a1, Qf[nb][1], acc, 0, 0, 0);
                    const v2h lo = pk_exp2_h2(acc[0], acc[1]);
                    const v2h hi = pk_exp2_h2(acc[2], acc[3]);
                    l_[nb] = __builtin_amdgcn_fdot2(lo, one2, l_[nb], false);
                    l_[nb] = __builtin_amdgcn_fdot2(hi, one2, l_[nb], false);
                    v4h p;
                    p[0] = lo[0]; p[1] = lo[1]; p[2] = hi[0]; p[3] = hi[1];
                    pp[half][nb] = p;
                }
            }
            // PV at K=32: B = concat(pp[0][nb], pp[1][nb]) = keys t2*32+8grp..+7
#pragma unroll
            for (int db = 0; db < 4; ++db) {
                v8h av = *(const v8h*)&Vts[cur][db * 16 + l15][t2 * 32 + grp * 8];
#pragma unroll
                for (int nb = 0; nb < 4; ++nb) {
                    v8h bb;
                    bb[0] = pp[0][nb][0]; bb[1] = pp[0][nb][1];
                    bb[2] = pp[0][nb][2]; bb[3] = pp[0][nb][3];
                    bb[4] = pp[1][nb][0]; bb[5] = pp[1][nb][1];
                    bb[6] = pp[1][nb][2]; bb[7] = pp[1][nb][3];
                    O[db][nb] = __builtin_amdgcn_mfma_f32_16x16x32_f16(av, bb, O[db][nb], 0, 0, 0);
                }
            }
        }
        __builtin_amdgcn_s_setprio(0);

        // stage tile t+1 (regs -> other LDS buffer); issue loads for tile t+2
        if (t < SEQ / 64 - 1) {
            *(v8h*)&Ks[cur ^ 1][srow][sseg * 16]      = kr0;
            *(v8h*)&Ks[cur ^ 1][srow][sseg * 16 + 8]  = kr1;
            *(v8h*)&Vts[cur ^ 1][srow][sseg * 16]     = vr0;
            *(v8h*)&Vts[cur ^ 1][srow][sseg * 16 + 8] = vr1;
            if (t < SEQ / 64 - 2) {
                const size_t ko = (size_t)(t + 2) * 64 * 64;
                const size_t vo = (size_t)(t + 2) * 64;
                kr0 = *(const v8h*)(kp + ko);
                kr1 = *(const v8h*)(kp + ko + 8);
                vr0 = *(const v8h*)(vp + vo);
                vr1 = *(const v8h*)(vp + vo + 8);
            }
        }
        __syncthreads();
    }

    // epilogue: reduce l over the 4 key-groups (grp), normalize, store fp16
#pragma unroll
    for (int nb = 0; nb < 4; ++nb) {
        float l = l_[nb];
        l += __shfl_xor(l, 16);
        l += __shfl_xor(l, 32);
        const float inv = 1.0f / l;
        const size_t row = (size_t)b * SEQ + qblk * 256 + w * 64 + nb * 16 + l15;
#pragma unroll
        for (int db = 0; db < 4; ++db) {
            v4h o;
            o[0] = (_Float16)(O[db][nb][0] * inv);
            o[1] = (_Float16)(O[db][nb][1] * inv);
            o[2] = (_Float16)(O[db][nb][2] * inv);
            o[3] = (_Float16)(O[db][nb][3] * inv);
            *(v4h*)(out + row * INNER + h * 64 + db * 16 + grp * 4) = o;
        }
    }
}

extern "C" void kernel_launch(void* const* d_in, const int* in_sizes, int n_in,
                              void* d_out, int out_size, void* d_ws, size_t ws_size,
                              hipStream_t stream) {
    const float* x     = (const float*)d_in[0];
    const float* ln_g  = (const float*)d_in[1];
    const float* ln_b  = (const float*)d_in[2];
    const float* w_qkv = (const float*)d_in[3];
    const float* w_out = (const float*)d_in[4];
    const float* b_out = (const float*)d_in[5];
    float* out = (float*)d_out;

    char* ws = (char*)d_ws;
    const size_t MB = 1024 * 1024;
    _Float16* xnh   = (_Float16*)(ws);               // [0,16) MB
    _Float16* W1t   = (_Float16*)(ws + 16 * MB);     // [16,22)
    _Float16* W2t   = (_Float16*)(ws + 22 * MB);     // [22,24)
    float2*   ropet = (float2*)(ws + 24 * MB);       // [24,25)
    _Float16* Qh    = (_Float16*)(ws + 72 * MB);     // [72,88)
    _Float16* Kh    = (_Float16*)(ws + 88 * MB);     // [88,104)
    _Float16* Vtg   = (_Float16*)(ws + 104 * MB);    // [104,120)
    _Float16* attnh = (_Float16*)(ws);               // reuse xnh (dead after fused gemm)

    // one merged preprocessing launch: LN + wcvt(Wqkv) + wcvt(Wout) + rope table
    prep_kernel<<<ROWS + 1024 + 512, 256, 0, stream>>>(
        x, ln_g, ln_b, xnh, w_qkv, W1t, w_out, W2t, ropet);

    gemm_qkv_rope<<<dim3(3 * INNER / 128, ROWS / 128), 256, 0, stream>>>(
        xnh, W1t, ropet, Qh, Kh, Vtg);

    fa_kernel<<<512, 256, 0, stream>>>(Qh, Kh, Vtg, attnh);

    gemm_nt_f<<<dim3(DIM / 128, ROWS / 128), 256, 0, stream>>>(
        attnh, W2t, b_out, out, ROWS, DIM, INNER);
}